// Round 1
// baseline (332.362 us; speedup 1.0000x reference)
//
#include <hip/hip_runtime.h>
#include <stdint.h>

#define NPIX   65536
#define NIMG   8
#define NCH    64
#define KSEL   2048
#define NFG    1024
#define NRING  768
#define NBG    256
#define INV_TEMP 14.285714285714286f   // 1/0.07

// ft staging geometry: cols [0,2048) = final rows, [2048,5120) = tie candidates
#define FTC    5120
// zero region = cnt(128B) + candcnt(128B) + map(1MB) = 1048832 B = 65552 float4
#define ZERO_F4 65552
#define ZERO_PER_BLK 257   // 257*256 blocks >= 65552

typedef __attribute__((ext_vector_type(8))) short bf16x8;
typedef __attribute__((ext_vector_type(4))) float f32x4;

// ---------------- Threefry-2x32 (20 rounds), exactly as JAX's lowering ------
__device__ __forceinline__ void tf2x32(uint32_t k0, uint32_t k1,
                                       uint32_t& x0, uint32_t& x1) {
  const uint32_t ks2 = k0 ^ k1 ^ 0x1BD11BDAu;
  x0 += k0; x1 += k1;
#define TF_RND(r) { x0 += x1; x1 = (x1 << (r)) | (x1 >> (32 - (r))); x1 ^= x0; }
  TF_RND(13) TF_RND(15) TF_RND(26) TF_RND(6)
  x0 += k1;  x1 += ks2 + 1u;
  TF_RND(17) TF_RND(29) TF_RND(16) TF_RND(24)
  x0 += ks2; x1 += k0 + 2u;
  TF_RND(13) TF_RND(15) TF_RND(26) TF_RND(6)
  x0 += k0;  x1 += k1 + 3u;
  TF_RND(17) TF_RND(29) TF_RND(16) TF_RND(24)
  x0 += k1;  x1 += ks2 + 4u;
  TF_RND(13) TF_RND(15) TF_RND(26) TF_RND(6)
  x0 += ks2; x1 += k0 + 5u;
#undef TF_RND
}

// float -> bf16 round-to-nearest-even
__device__ __forceinline__ ushort f2bf(float f) {
  uint32_t u = __float_as_uint(f);
  return (ushort)((u + 0x7FFFu + ((u >> 16) & 1u)) >> 16);
}

// ---------------- K1: fused dilation + hash + per-band histogram ------------
// 256 blocks = 8 images x 32 bands of 8 rows (halo 10 each side -> 28 rows).
// Also: zero {cnt,candcnt,map} chunkwise, derive keys per block (parallel).
__global__ __launch_bounds__(256) void prep_hash(const int* __restrict__ labels,
                                                 float4* __restrict__ zreg,
                                                 uint32_t* __restrict__ mgrp,
                                                 uint32_t* __restrict__ hist32,
                                                 float* __restrict__ out) {
  __shared__ uint64_t fgs[112], hds[112], fgb[32], dlb[32];  // 28 rows x 4 words
  __shared__ uint32_t lh[768];
  __shared__ uint32_t skeys[6];
  const int tid = threadIdx.x;
  const int img = blockIdx.x >> 5;
  const int band = blockIdx.x & 31;

  // distributed zero of cnt+candcnt+map (consumed by K2, no intra-kernel race)
  {
    int start = blockIdx.x * ZERO_PER_BLK;
    int end = start + ZERO_PER_BLK; if (end > ZERO_F4) end = ZERO_F4;
    for (int i = start + tid; i < end; i += 256)
      zreg[i] = make_float4(0.f, 0.f, 0.f, 0.f);
  }
  if (blockIdx.x == 0 && tid == 0) out[0] = 0.0f;

  // JAX partitionable split: key(1) fold img, then fold group g
  if (tid < 3) {
    uint32_t kb0 = 0u, kb1 = (uint32_t)img;
    tf2x32(0u, 1u, kb0, kb1);
    uint32_t x0 = 0u, x1 = (uint32_t)tid;
    tf2x32(kb0, kb1, x0, x1);
    skeys[tid * 2 + 0] = x0;
    skeys[tid * 2 + 1] = x1;
  }
  for (int t = tid; t < 768; t += 256) lh[t] = 0;

  // pack fg bits for rows [band*8-10, band*8+18) (clamped rows contribute 0)
  const int rbase = band * 8 - 10;
  for (int it = 0; it < 28; ++it) {
    int hr = rbase + it;
    bool bit = false;
    if (hr >= 0 && hr < 256) bit = (labels[(img << 16) + (hr << 8) + tid] == 1);
    uint64_t m = __ballot(bit);
    if ((tid & 63) == 0) fgs[it * 4 + (tid >> 6)] = m;
  }
  __syncthreads();

  // horizontal dilation radius 10 within each row
  for (int w = tid; w < 112; w += 256) {
    int wc = w & 3;
    uint64_t x = fgs[w];
    uint64_t L = wc > 0 ? fgs[w - 1] : 0ull;
    uint64_t R = wc < 3 ? fgs[w + 1] : 0ull;
    uint64_t acc = x;
    #pragma unroll
    for (int s = 1; s <= 10; ++s) {
      acc |= (x << s) | (L >> (64 - s));
      acc |= (x >> s) | (R << (64 - s));
    }
    hds[w] = acc;
  }
  __syncthreads();

  // vertical dilation radius 10 for the band's 8 output rows
  for (int w = tid; w < 32; w += 256) {
    int r = w >> 2, wc = w & 3;
    uint64_t acc = 0ull;
    #pragma unroll
    for (int dr = 0; dr <= 20; ++dr) acc |= hds[(r + dr) * 4 + wc];
    fgb[w] = fgs[(r + 10) * 4 + wc];
    dlb[w] = acc;
  }
  __syncthreads();

  const uint32_t K00 = skeys[0], K01 = skeys[1];
  const uint32_t K10 = skeys[2], K11 = skeys[3];
  const uint32_t K20 = skeys[4], K21 = skeys[5];
  const int pbase = blockIdx.x * 2048;        // == img*65536 + band*2048

  #pragma unroll
  for (int k = 0; k < 8; ++k) {
    int off = k * 256 + tid;                  // 0..2047 within band
    int pix = (pbase + off) & 65535;
    int lw = off >> 6, bp = off & 63;
    uint32_t fgbit = (uint32_t)((fgb[lw] >> bp) & 1ull);
    uint32_t dilbit = (uint32_t)((dlb[lw] >> bp) & 1ull);
    uint32_t grp = fgbit ? 0u : (dilbit ? 1u : 2u);
    uint32_t k0 = grp == 0 ? K00 : grp == 1 ? K10 : K20;
    uint32_t k1 = grp == 0 ? K01 : grp == 1 ? K11 : K21;
    uint32_t x0 = 0u, x1 = (uint32_t)pix;
    tf2x32(k0, k1, x0, x1);
    uint32_t m = (x0 ^ x1) >> 9;
    mgrp[pbase + off] = (m << 2) | grp;
    atomicAdd(&lh[grp * 256 + (m >> 15)], 1u);
  }
  __syncthreads();
  // non-atomic per-band histogram part (summed in K2) -> no pre-zero needed
  for (int t = tid; t < 768; t += 256) hist32[blockIdx.x * 768 + t] = lh[t];
}

// ---------------- K2: thresholds + emit pixel->slot map ---------------------
__global__ __launch_bounds__(256) void topk_map(const uint32_t* __restrict__ mgrp,
                                                const uint32_t* __restrict__ hist32,
                                                uint32_t* __restrict__ TG,
                                                uint32_t* __restrict__ cnt,
                                                uint32_t* __restrict__ candcnt,
                                                unsigned long long* __restrict__ cand,
                                                ushort* __restrict__ map) {
  __shared__ uint32_t hh[768];
  __shared__ uint32_t sT[3], loc[3], lbd[3], basA[3], basB[3];
  const int tid = threadIdx.x;
  const int b = blockIdx.x >> 5;
  const int base = blockIdx.x * 2048;
  for (int t = tid; t < 768; t += 256) {
    uint32_t s = 0;
    const uint32_t* hp = hist32 + (size_t)b * 32 * 768 + t;
    #pragma unroll
    for (int band = 0; band < 32; ++band) s += hp[band * 768];
    hh[t] = s;
  }
  if (tid < 3) { loc[tid] = 0; lbd[tid] = 0; }
  __syncthreads();

  if (tid < 3) {
    uint32_t nsel = tid == 0 ? NFG : tid == 1 ? NRING : NBG;
    const uint32_t* h = hh + tid * 256;
    uint32_t cum = 0; int T = 255;
    for (; T > 0; --T) {
      uint32_t c = h[T];
      if (cum + c >= nsel) break;
      cum += c;
    }
    sT[tid] = (uint32_t)T;
    if ((blockIdx.x & 31) == 0) {
      TG[(b * 3 + tid) * 2] = (uint32_t)T;
      TG[(b * 3 + tid) * 2 + 1] = cum;      // count strictly above bucket T
    }
  }
  __syncthreads();
  const uint32_t T0 = sT[0], T1 = sT[1], T2 = sT[2];

  #pragma unroll
  for (int k = 0; k < 8; ++k) {
    uint32_t v = mgrp[base + k * 256 + tid];
    uint32_t g = v & 3u, bin = v >> 17;
    uint32_t T = g == 0 ? T0 : g == 1 ? T1 : T2;
    if (bin > T) atomicAdd(&loc[g], 1u);
    else if (bin == T) atomicAdd(&lbd[g], 1u);
  }
  __syncthreads();
  if (tid < 3) {
    basA[tid] = atomicAdd(&cnt[b * 3 + tid], loc[tid]);
    basB[tid] = atomicAdd(&candcnt[b * 3 + tid], lbd[tid]);
    loc[tid] = 0; lbd[tid] = 0;
  }
  __syncthreads();

  #pragma unroll
  for (int k = 0; k < 8; ++k) {
    int p = base + k * 256 + tid;
    uint32_t v = mgrp[p];
    uint32_t g = v & 3u, bin = v >> 17;
    uint32_t T = g == 0 ? T0 : g == 1 ? T1 : T2;
    int pix = p & 65535;
    if (bin > T) {
      uint32_t o = atomicAdd(&loc[g], 1u);
      int segb = g == 0 ? 0 : g == 1 ? NFG : (NFG + NRING);
      map[(b << 16) + pix] = (ushort)(segb + (int)(basA[g] + o) + 1);
    } else if (bin == T) {
      uint32_t o = atomicAdd(&lbd[g], 1u);
      uint32_t c = basB[g] + o;
      uint32_t m = v >> 2;
      if (c < 1024u) {
        cand[((size_t)b * 3 + g) * 1024 + c] =
            ((unsigned long long)m << 16) | (uint32_t)pix;
        map[(b << 16) + pix] = (ushort)(2048 + (int)g * 1024 + (int)c + 1);
      }
    }
  }
}

// ---------------- K3: dense feats stream -> compacted f32 columns ----------
// 512 blocks = 64 channels x 8 images; img = bid&7 keeps each image's map/ft
// on one XCD's L2. Coalesced float4 reads of the plane + coalesced u16 map.
__global__ __launch_bounds__(256) void stream_compact(const float* __restrict__ feats,
                                                      const ushort* __restrict__ map,
                                                      float* __restrict__ ft) {
  const int img = blockIdx.x & 7;
  const int ch = blockIdx.x >> 3;
  const float4* plane = (const float4*)(feats + ((size_t)(img * 64 + ch)) * NPIX);
  const uint2* m4 = (const uint2*)(map + (size_t)img * NPIX);
  float* fto = ft + (size_t)(img * 64 + ch) * FTC;
  for (int i = threadIdx.x; i < NPIX / 4; i += 256) {
    float4 v = plane[i];
    uint2 mm = m4[i];
    uint32_t s;
    s = mm.x & 0xFFFFu; if (s) fto[s - 1] = v.x;
    s = mm.x >> 16;     if (s) fto[s - 1] = v.y;
    s = mm.y & 0xFFFFu; if (s) fto[s - 1] = v.z;
    s = mm.y >> 16;     if (s) fto[s - 1] = v.w;
  }
}

// ---------------- K4: tie-rank + normalize + transpose -> bf16 rows ---------
// 128 blocks = 8 images x 16 slot-tiles of 128. Reads ft columns (L2-hot,
// coalesced across threads per channel), reproduces the exact f32 summation
// order of the old gather (ss over k, tot over q), writes fs[row][64] bf16.
__global__ __launch_bounds__(128) void norm_write(const float* __restrict__ ft,
                                                  const uint32_t* __restrict__ TG,
                                                  const uint32_t* __restrict__ candcnt,
                                                  const unsigned long long* __restrict__ cand,
                                                  ushort* __restrict__ fs) {
  __shared__ unsigned long long cb[1024];
  __shared__ ushort rk2j[1024];
  const int tid = threadIdx.x;
  const int img = blockIdx.x & 7;
  const int tile = blockIdx.x >> 3;
  const int s0 = tile * 128;
  int g, segb, nsel;
  if (tile < 8)       { g = 0; segb = 0;           nsel = NFG; }
  else if (tile < 14) { g = 1; segb = NFG;         nsel = NRING; }
  else                { g = 2; segb = NFG + NRING; nsel = NBG; }
  const int task = img * 3 + g;
  const uint32_t G = TG[task * 2 + 1];
  const int lo = s0 - segb;                  // slot-in-segment of first thread

  if (lo + 127 >= (int)G) {                  // block-uniform: ranks needed
    const int c = (int)(candcnt[task] < 1024u ? candcnt[task] : 1024u);
    const int r = nsel - (int)G;
    for (int i = tid; i < c; i += 128) cb[i] = cand[(size_t)task * 1024 + i];
    __syncthreads();
    for (int i = tid; i < c; i += 128) {
      unsigned long long me = cb[i];
      uint32_t mm = (uint32_t)(me >> 16), pi = (uint32_t)(me & 0xFFFFu);
      int rank = 0;
      for (int j = 0; j < c; ++j) {
        unsigned long long o = cb[j];
        uint32_t om = (uint32_t)(o >> 16), op = (uint32_t)(o & 0xFFFFu);
        if (om > mm || (om == mm && op < pi)) ++rank;
      }
      if (rank < r) rk2j[rank] = (ushort)i;
    }
    __syncthreads();
  }

  const int sl = lo + tid;
  int col;
  if (sl < (int)G) col = s0 + tid;                          // final-row column
  else col = 2048 + g * 1024 + (int)rk2j[sl - (int)G];      // candidate column

  const float* fb = ft + (size_t)img * 64 * FTC + col;
  float v[64];
  float tot = 0.f;
  #pragma unroll
  for (int q = 0; q < 16; ++q) {
    float ss = 0.f;
    #pragma unroll
    for (int k = 0; k < 4; ++k) {
      float x = fb[(size_t)(q * 4 + k) * FTC];
      v[q * 4 + k] = x;
      ss += x * x;
    }
    tot += ss;
  }
  const float sc = 1.0f / fmaxf(sqrtf(tot), 1e-12f);
  ushort* row = fs + ((size_t)img * KSEL + s0 + tid) * NCH;
  #pragma unroll
  for (int c4 = 0; c4 < 16; ++c4) {
    ushort4 o4;
    o4.x = f2bf(v[c4 * 4 + 0] * sc);
    o4.y = f2bf(v[c4 * 4 + 1] * sc);
    o4.z = f2bf(v[c4 * 4 + 2] * sc);
    o4.w = f2bf(v[c4 * 4 + 3] * sc);
    ((ushort4*)row)[c4] = o4;
  }
}

// ---------------- K5: MFMA loss (unchanged) ---------------------------------
__global__ __launch_bounds__(256) void loss_mfma(const ushort* __restrict__ fs,
                                                 float* __restrict__ out) {
  const int img = blockIdx.x & 7;             // XCD swizzle
  const int a0 = (blockIdx.x >> 3) * 32;
  const ushort* X = fs + (size_t)img * KSEL * NCH;
  const int tid = threadIdx.x;
  const int lane = tid & 63, wave = tid >> 6;
  const int quad = lane >> 4, col = lane & 15;
  const int rt = wave >> 1, colh = wave & 1;

  __shared__ float redD[2][2][16];
  __shared__ float redP[2][16];

  const int arow = a0 + rt * 16 + col;
  const bf16x8* Ap = (const bf16x8*)(X + (size_t)arow * NCH + quad * 8);
  const bf16x8 a_lo = Ap[0];
  const bf16x8 a_hi = Ap[4];                  // +32 channels = +64 B

  float pD[4] = {0.f, 0.f, 0.f, 0.f};
  float pP[4] = {0.f, 0.f, 0.f, 0.f};
  const int ct0 = colh * 64;
  const int mbase = a0 + rt * 16 + quad * 4;  // D rows for this lane

  for (int ct = ct0; ct < ct0 + 64; ++ct) {
    const int j = ct * 16 + col;              // D column for this lane
    const bf16x8* Bp = (const bf16x8*)(X + (size_t)j * NCH + quad * 8);
    bf16x8 b_lo = Bp[0];
    bf16x8 b_hi = Bp[4];
    f32x4 d = {0.f, 0.f, 0.f, 0.f};
    d = __builtin_amdgcn_mfma_f32_16x16x32_bf16(a_lo, b_lo, d, 0, 0, 0);
    d = __builtin_amdgcn_mfma_f32_16x16x32_bf16(a_hi, b_hi, d, 0, 0, 0);
    #pragma unroll
    for (int r = 0; r < 4; ++r) {
      float e = __expf(d[r] * INV_TEMP);
      if (j == mbase + r) e = 0.f;            // ~eye (only hits in colh 0)
      pD[r] += e;
      if (colh == 0) pP[r] += e;              // fg columns = tiles 0..63
    }
  }

  #pragma unroll
  for (int o = 1; o < 16; o <<= 1) {
    #pragma unroll
    for (int r = 0; r < 4; ++r) {
      pD[r] += __shfl_xor(pD[r], o);
      pP[r] += __shfl_xor(pP[r], o);
    }
  }
  if (col == 0) {
    #pragma unroll
    for (int r = 0; r < 4; ++r) {
      redD[rt][colh][quad * 4 + r] = pD[r];
      if (colh == 0) redP[rt][quad * 4 + r] = pP[r];
    }
  }
  __syncthreads();

  float term = 0.f;
  if (tid < 32) {
    int lrt = tid >> 4, lr = tid & 15;
    float dsum = fmaxf(redD[lrt][0][lr] + redD[lrt][1][lr], 1e-8f);
    float psum = fmaxf(redP[lrt][lr], 1e-8f);
    term = __logf(dsum) - __logf(psum);
  }
  if (tid < 64) {
    #pragma unroll
    for (int o = 32; o > 0; o >>= 1) term += __shfl_xor(term, o);
    if (tid == 0) atomicAdd(out, term * (1.0f / (NFG * NIMG)));
  }
}

// ---------------- launcher ---------------------------------------------------
extern "C" void kernel_launch(void* const* d_in, const int* in_sizes, int n_in,
                              void* d_out, int out_size, void* d_ws, size_t ws_size,
                              hipStream_t stream) {
  const float* feats = (const float*)d_in[0];
  const int* labels  = (const int*)d_in[1];
  float* out = (float*)d_out;

  char* ws = (char*)d_ws;
  uint32_t* TG      = (uint32_t*)(ws);                      // 192 B
  // --- zero region @4096: cnt(128) + candcnt(128) + map(1 MB) -------------
  uint32_t* cnt     = (uint32_t*)(ws + 4096);
  uint32_t* candcnt = (uint32_t*)(ws + 4224);
  ushort*   map     = (ushort*)(ws + 4352);                 // ends 1052928
  float4*   zreg    = (float4*)(ws + 4096);
  // ------------------------------------------------------------------------
  unsigned long long* cand = (unsigned long long*)(ws + 1052928); // 192 KB
  uint32_t* mgrp    = (uint32_t*)(ws + 2097152);            // 2 MB [8][65536]
  uint32_t* hist32  = (uint32_t*)(ws + 4194304);            // 768 KB [8][32][768]
  float*    ft      = (float*)(ws + 8388608);               // 10.5 MB [8][64][5120]
  ushort*   fs      = (ushort*)(ws + 18874368);             // 2 MB bf16 [8][2048][64]

  hipLaunchKernelGGL(prep_hash, dim3(NIMG * 32), dim3(256), 0, stream,
                     labels, zreg, mgrp, hist32, out);
  hipLaunchKernelGGL(topk_map, dim3(NIMG * 32), dim3(256), 0, stream,
                     mgrp, hist32, TG, cnt, candcnt, cand, map);
  hipLaunchKernelGGL(stream_compact, dim3(NCH * NIMG), dim3(256), 0, stream,
                     feats, map, ft);
  hipLaunchKernelGGL(norm_write, dim3(NIMG * 16), dim3(128), 0, stream,
                     ft, TG, candcnt, cand, fs);
  hipLaunchKernelGGL(loss_mfma, dim3(NIMG * (NFG / 32)), dim3(256), 0, stream,
                     fs, out);
}

// Round 2
// 274.861 us; speedup vs baseline: 1.2092x; 1.2092x over previous
//
#include <hip/hip_runtime.h>
#include <stdint.h>

#define NPIX   65536
#define NIMG   8
#define NCH    64
#define KSEL   2048
#define NFG    1024
#define NRING  768
#define NBG    256
#define INV_TEMP 14.285714285714286f   // 1/0.07

// ft staging geometry: cols [0,2048) = final rows, [2048,5120) = tie candidates
#define FTC    5120
// zero region = cnt(128B) + candcnt(128B) + map(1MB) = 1048832 B = 65552 float4
#define ZERO_F4 65552
#define ZERO_PER_BLK 257   // 257*256 blocks >= 65552

typedef __attribute__((ext_vector_type(8))) short bf16x8;
typedef __attribute__((ext_vector_type(4))) float f32x4;

// ---------------- Threefry-2x32 (20 rounds), exactly as JAX's lowering ------
__device__ __forceinline__ void tf2x32(uint32_t k0, uint32_t k1,
                                       uint32_t& x0, uint32_t& x1) {
  const uint32_t ks2 = k0 ^ k1 ^ 0x1BD11BDAu;
  x0 += k0; x1 += k1;
#define TF_RND(r) { x0 += x1; x1 = (x1 << (r)) | (x1 >> (32 - (r))); x1 ^= x0; }
  TF_RND(13) TF_RND(15) TF_RND(26) TF_RND(6)
  x0 += k1;  x1 += ks2 + 1u;
  TF_RND(17) TF_RND(29) TF_RND(16) TF_RND(24)
  x0 += ks2; x1 += k0 + 2u;
  TF_RND(13) TF_RND(15) TF_RND(26) TF_RND(6)
  x0 += k0;  x1 += k1 + 3u;
  TF_RND(17) TF_RND(29) TF_RND(16) TF_RND(24)
  x0 += k1;  x1 += ks2 + 4u;
  TF_RND(13) TF_RND(15) TF_RND(26) TF_RND(6)
  x0 += ks2; x1 += k0 + 5u;
#undef TF_RND
}

// float -> bf16 round-to-nearest-even
__device__ __forceinline__ ushort f2bf(float f) {
  uint32_t u = __float_as_uint(f);
  return (ushort)((u + 0x7FFFu + ((u >> 16) & 1u)) >> 16);
}

// ---------------- K1: fused dilation + hash + per-band histogram ------------
// 256 blocks = 8 images x 32 bands of 8 rows (halo 10 each side -> 28 rows).
// Also: zero {cnt,candcnt,map} chunkwise, derive keys per block (parallel).
__global__ __launch_bounds__(256) void prep_hash(const int* __restrict__ labels,
                                                 float4* __restrict__ zreg,
                                                 uint32_t* __restrict__ mgrp,
                                                 uint32_t* __restrict__ hist32,
                                                 float* __restrict__ out) {
  __shared__ uint64_t fgs[112], hds[112], fgb[32], dlb[32];  // 28 rows x 4 words
  __shared__ uint32_t lh[768];
  __shared__ uint32_t skeys[6];
  const int tid = threadIdx.x;
  const int img = blockIdx.x >> 5;
  const int band = blockIdx.x & 31;

  // distributed zero of cnt+candcnt+map (consumed by K2, no intra-kernel race)
  {
    int start = blockIdx.x * ZERO_PER_BLK;
    int end = start + ZERO_PER_BLK; if (end > ZERO_F4) end = ZERO_F4;
    for (int i = start + tid; i < end; i += 256)
      zreg[i] = make_float4(0.f, 0.f, 0.f, 0.f);
  }
  if (blockIdx.x == 0 && tid == 0) out[0] = 0.0f;

  // JAX partitionable split: key(1) fold img, then fold group g
  if (tid < 3) {
    uint32_t kb0 = 0u, kb1 = (uint32_t)img;
    tf2x32(0u, 1u, kb0, kb1);
    uint32_t x0 = 0u, x1 = (uint32_t)tid;
    tf2x32(kb0, kb1, x0, x1);
    skeys[tid * 2 + 0] = x0;
    skeys[tid * 2 + 1] = x1;
  }
  for (int t = tid; t < 768; t += 256) lh[t] = 0;

  // pack fg bits for rows [band*8-10, band*8+18) (clamped rows contribute 0)
  const int rbase = band * 8 - 10;
  for (int it = 0; it < 28; ++it) {
    int hr = rbase + it;
    bool bit = false;
    if (hr >= 0 && hr < 256) bit = (labels[(img << 16) + (hr << 8) + tid] == 1);
    uint64_t m = __ballot(bit);
    if ((tid & 63) == 0) fgs[it * 4 + (tid >> 6)] = m;
  }
  __syncthreads();

  // horizontal dilation radius 10 within each row
  for (int w = tid; w < 112; w += 256) {
    int wc = w & 3;
    uint64_t x = fgs[w];
    uint64_t L = wc > 0 ? fgs[w - 1] : 0ull;
    uint64_t R = wc < 3 ? fgs[w + 1] : 0ull;
    uint64_t acc = x;
    #pragma unroll
    for (int s = 1; s <= 10; ++s) {
      acc |= (x << s) | (L >> (64 - s));
      acc |= (x >> s) | (R << (64 - s));
    }
    hds[w] = acc;
  }
  __syncthreads();

  // vertical dilation radius 10 for the band's 8 output rows
  for (int w = tid; w < 32; w += 256) {
    int r = w >> 2, wc = w & 3;
    uint64_t acc = 0ull;
    #pragma unroll
    for (int dr = 0; dr <= 20; ++dr) acc |= hds[(r + dr) * 4 + wc];
    fgb[w] = fgs[(r + 10) * 4 + wc];
    dlb[w] = acc;
  }
  __syncthreads();

  const uint32_t K00 = skeys[0], K01 = skeys[1];
  const uint32_t K10 = skeys[2], K11 = skeys[3];
  const uint32_t K20 = skeys[4], K21 = skeys[5];
  const int pbase = blockIdx.x * 2048;        // == img*65536 + band*2048

  #pragma unroll
  for (int k = 0; k < 8; ++k) {
    int off = k * 256 + tid;                  // 0..2047 within band
    int pix = (pbase + off) & 65535;
    int lw = off >> 6, bp = off & 63;
    uint32_t fgbit = (uint32_t)((fgb[lw] >> bp) & 1ull);
    uint32_t dilbit = (uint32_t)((dlb[lw] >> bp) & 1ull);
    uint32_t grp = fgbit ? 0u : (dilbit ? 1u : 2u);
    uint32_t k0 = grp == 0 ? K00 : grp == 1 ? K10 : K20;
    uint32_t k1 = grp == 0 ? K01 : grp == 1 ? K11 : K21;
    uint32_t x0 = 0u, x1 = (uint32_t)pix;
    tf2x32(k0, k1, x0, x1);
    uint32_t m = (x0 ^ x1) >> 9;
    mgrp[pbase + off] = (m << 2) | grp;
    atomicAdd(&lh[grp * 256 + (m >> 15)], 1u);
  }
  __syncthreads();
  // non-atomic per-band histogram part (summed in K2) -> no pre-zero needed
  for (int t = tid; t < 768; t += 256) hist32[blockIdx.x * 768 + t] = lh[t];
}

// ---------------- K2: thresholds + emit pixel->slot map ---------------------
__global__ __launch_bounds__(256) void topk_map(const uint32_t* __restrict__ mgrp,
                                                const uint32_t* __restrict__ hist32,
                                                uint32_t* __restrict__ TG,
                                                uint32_t* __restrict__ cnt,
                                                uint32_t* __restrict__ candcnt,
                                                unsigned long long* __restrict__ cand,
                                                ushort* __restrict__ map) {
  __shared__ uint32_t hh[768];
  __shared__ uint32_t sT[3], loc[3], lbd[3], basA[3], basB[3];
  const int tid = threadIdx.x;
  const int b = blockIdx.x >> 5;
  const int base = blockIdx.x * 2048;
  for (int t = tid; t < 768; t += 256) {
    uint32_t s = 0;
    const uint32_t* hp = hist32 + (size_t)b * 32 * 768 + t;
    #pragma unroll
    for (int band = 0; band < 32; ++band) s += hp[band * 768];
    hh[t] = s;
  }
  if (tid < 3) { loc[tid] = 0; lbd[tid] = 0; }
  __syncthreads();

  if (tid < 3) {
    uint32_t nsel = tid == 0 ? NFG : tid == 1 ? NRING : NBG;
    const uint32_t* h = hh + tid * 256;
    uint32_t cum = 0; int T = 255;
    for (; T > 0; --T) {
      uint32_t c = h[T];
      if (cum + c >= nsel) break;
      cum += c;
    }
    sT[tid] = (uint32_t)T;
    if ((blockIdx.x & 31) == 0) {
      TG[(b * 3 + tid) * 2] = (uint32_t)T;
      TG[(b * 3 + tid) * 2 + 1] = cum;      // count strictly above bucket T
    }
  }
  __syncthreads();
  const uint32_t T0 = sT[0], T1 = sT[1], T2 = sT[2];

  #pragma unroll
  for (int k = 0; k < 8; ++k) {
    uint32_t v = mgrp[base + k * 256 + tid];
    uint32_t g = v & 3u, bin = v >> 17;
    uint32_t T = g == 0 ? T0 : g == 1 ? T1 : T2;
    if (bin > T) atomicAdd(&loc[g], 1u);
    else if (bin == T) atomicAdd(&lbd[g], 1u);
  }
  __syncthreads();
  if (tid < 3) {
    basA[tid] = atomicAdd(&cnt[b * 3 + tid], loc[tid]);
    basB[tid] = atomicAdd(&candcnt[b * 3 + tid], lbd[tid]);
    loc[tid] = 0; lbd[tid] = 0;
  }
  __syncthreads();

  #pragma unroll
  for (int k = 0; k < 8; ++k) {
    int p = base + k * 256 + tid;
    uint32_t v = mgrp[p];
    uint32_t g = v & 3u, bin = v >> 17;
    uint32_t T = g == 0 ? T0 : g == 1 ? T1 : T2;
    int pix = p & 65535;
    if (bin > T) {
      uint32_t o = atomicAdd(&loc[g], 1u);
      int segb = g == 0 ? 0 : g == 1 ? NFG : (NFG + NRING);
      map[(b << 16) + pix] = (ushort)(segb + (int)(basA[g] + o) + 1);
    } else if (bin == T) {
      uint32_t o = atomicAdd(&lbd[g], 1u);
      uint32_t c = basB[g] + o;
      uint32_t m = v >> 2;
      if (c < 1024u) {
        cand[((size_t)b * 3 + g) * 1024 + c] =
            ((unsigned long long)m << 16) | (uint32_t)pix;
        map[(b << 16) + pix] = (ushort)(2048 + (int)g * 1024 + (int)c + 1);
      }
    }
  }
}

// ---------------- K3: dense feats stream -> compacted f32 columns ----------
// 2048 blocks = 4 chunks x 64 channels x 8 images; img = bid&7 keeps each
// image's map/ft on one XCD's L2. Unrolled 4x: 4 float4 + 4 uint2 loads in
// flight before any consumption -> ~48 VGPR of MLP; 8 blocks/CU occupancy.
__global__ __launch_bounds__(256, 8) void stream_compact(const float* __restrict__ feats,
                                                         const ushort* __restrict__ map,
                                                         float* __restrict__ ft) {
  const int img = blockIdx.x & 7;
  const int ch = (blockIdx.x >> 3) & 63;
  const int chunk = blockIdx.x >> 9;           // 0..3, 16384 pixels each
  const float4* plane = (const float4*)(feats + ((size_t)(img * 64 + ch)) * NPIX)
                        + chunk * 4096;
  const uint2* m4 = (const uint2*)(map + (size_t)img * NPIX) + chunk * 4096;
  float* fto = ft + (size_t)(img * 64 + ch) * FTC;

  int i = threadIdx.x;
  #pragma unroll
  for (int it = 0; it < 4; ++it) {
    // issue all 8 loads before consuming any
    float4 v0 = plane[i];
    float4 v1 = plane[i + 256];
    float4 v2 = plane[i + 512];
    float4 v3 = plane[i + 768];
    uint2 m0 = m4[i];
    uint2 m1 = m4[i + 256];
    uint2 m2 = m4[i + 512];
    uint2 m3 = m4[i + 768];
    uint32_t s;
    s = m0.x & 0xFFFFu; if (s) fto[s - 1] = v0.x;
    s = m0.x >> 16;     if (s) fto[s - 1] = v0.y;
    s = m0.y & 0xFFFFu; if (s) fto[s - 1] = v0.z;
    s = m0.y >> 16;     if (s) fto[s - 1] = v0.w;
    s = m1.x & 0xFFFFu; if (s) fto[s - 1] = v1.x;
    s = m1.x >> 16;     if (s) fto[s - 1] = v1.y;
    s = m1.y & 0xFFFFu; if (s) fto[s - 1] = v1.z;
    s = m1.y >> 16;     if (s) fto[s - 1] = v1.w;
    s = m2.x & 0xFFFFu; if (s) fto[s - 1] = v2.x;
    s = m2.x >> 16;     if (s) fto[s - 1] = v2.y;
    s = m2.y & 0xFFFFu; if (s) fto[s - 1] = v2.z;
    s = m2.y >> 16;     if (s) fto[s - 1] = v2.w;
    s = m3.x & 0xFFFFu; if (s) fto[s - 1] = v3.x;
    s = m3.x >> 16;     if (s) fto[s - 1] = v3.y;
    s = m3.y & 0xFFFFu; if (s) fto[s - 1] = v3.z;
    s = m3.y >> 16;     if (s) fto[s - 1] = v3.w;
    i += 1024;
  }
}

// ---------------- K4: tie-rank + normalize + transpose -> bf16 rows ---------
// 128 blocks = 8 images x 16 slot-tiles of 128. Reads ft columns (L2-hot,
// coalesced across threads per channel), reproduces the exact f32 summation
// order of the old gather (ss over k, tot over q), writes fs[row][64] bf16.
__global__ __launch_bounds__(128) void norm_write(const float* __restrict__ ft,
                                                  const uint32_t* __restrict__ TG,
                                                  const uint32_t* __restrict__ candcnt,
                                                  const unsigned long long* __restrict__ cand,
                                                  ushort* __restrict__ fs) {
  __shared__ unsigned long long cb[1024];
  __shared__ ushort rk2j[1024];
  const int tid = threadIdx.x;
  const int img = blockIdx.x & 7;
  const int tile = blockIdx.x >> 3;
  const int s0 = tile * 128;
  int g, segb, nsel;
  if (tile < 8)       { g = 0; segb = 0;           nsel = NFG; }
  else if (tile < 14) { g = 1; segb = NFG;         nsel = NRING; }
  else                { g = 2; segb = NFG + NRING; nsel = NBG; }
  const int task = img * 3 + g;
  const uint32_t G = TG[task * 2 + 1];
  const int lo = s0 - segb;                  // slot-in-segment of first thread

  if (lo + 127 >= (int)G) {                  // block-uniform: ranks needed
    const int c = (int)(candcnt[task] < 1024u ? candcnt[task] : 1024u);
    const int r = nsel - (int)G;
    for (int i = tid; i < c; i += 128) cb[i] = cand[(size_t)task * 1024 + i];
    __syncthreads();
    for (int i = tid; i < c; i += 128) {
      unsigned long long me = cb[i];
      uint32_t mm = (uint32_t)(me >> 16), pi = (uint32_t)(me & 0xFFFFu);
      int rank = 0;
      for (int j = 0; j < c; ++j) {
        unsigned long long o = cb[j];
        uint32_t om = (uint32_t)(o >> 16), op = (uint32_t)(o & 0xFFFFu);
        if (om > mm || (om == mm && op < pi)) ++rank;
      }
      if (rank < r) rk2j[rank] = (ushort)i;
    }
    __syncthreads();
  }

  const int sl = lo + tid;
  int col;
  if (sl < (int)G) col = s0 + tid;                          // final-row column
  else col = 2048 + g * 1024 + (int)rk2j[sl - (int)G];      // candidate column

  const float* fb = ft + (size_t)img * 64 * FTC + col;
  float v[64];
  float tot = 0.f;
  #pragma unroll
  for (int q = 0; q < 16; ++q) {
    float ss = 0.f;
    #pragma unroll
    for (int k = 0; k < 4; ++k) {
      float x = fb[(size_t)(q * 4 + k) * FTC];
      v[q * 4 + k] = x;
      ss += x * x;
    }
    tot += ss;
  }
  const float sc = 1.0f / fmaxf(sqrtf(tot), 1e-12f);
  ushort* row = fs + ((size_t)img * KSEL + s0 + tid) * NCH;
  #pragma unroll
  for (int c4 = 0; c4 < 16; ++c4) {
    ushort4 o4;
    o4.x = f2bf(v[c4 * 4 + 0] * sc);
    o4.y = f2bf(v[c4 * 4 + 1] * sc);
    o4.z = f2bf(v[c4 * 4 + 2] * sc);
    o4.w = f2bf(v[c4 * 4 + 3] * sc);
    ((ushort4*)row)[c4] = o4;
  }
}

// ---------------- K5: MFMA loss (unchanged) ---------------------------------
__global__ __launch_bounds__(256) void loss_mfma(const ushort* __restrict__ fs,
                                                 float* __restrict__ out) {
  const int img = blockIdx.x & 7;             // XCD swizzle
  const int a0 = (blockIdx.x >> 3) * 32;
  const ushort* X = fs + (size_t)img * KSEL * NCH;
  const int tid = threadIdx.x;
  const int lane = tid & 63, wave = tid >> 6;
  const int quad = lane >> 4, col = lane & 15;
  const int rt = wave >> 1, colh = wave & 1;

  __shared__ float redD[2][2][16];
  __shared__ float redP[2][16];

  const int arow = a0 + rt * 16 + col;
  const bf16x8* Ap = (const bf16x8*)(X + (size_t)arow * NCH + quad * 8);
  const bf16x8 a_lo = Ap[0];
  const bf16x8 a_hi = Ap[4];                  // +32 channels = +64 B

  float pD[4] = {0.f, 0.f, 0.f, 0.f};
  float pP[4] = {0.f, 0.f, 0.f, 0.f};
  const int ct0 = colh * 64;
  const int mbase = a0 + rt * 16 + quad * 4;  // D rows for this lane

  for (int ct = ct0; ct < ct0 + 64; ++ct) {
    const int j = ct * 16 + col;              // D column for this lane
    const bf16x8* Bp = (const bf16x8*)(X + (size_t)j * NCH + quad * 8);
    bf16x8 b_lo = Bp[0];
    bf16x8 b_hi = Bp[4];
    f32x4 d = {0.f, 0.f, 0.f, 0.f};
    d = __builtin_amdgcn_mfma_f32_16x16x32_bf16(a_lo, b_lo, d, 0, 0, 0);
    d = __builtin_amdgcn_mfma_f32_16x16x32_bf16(a_hi, b_hi, d, 0, 0, 0);
    #pragma unroll
    for (int r = 0; r < 4; ++r) {
      float e = __expf(d[r] * INV_TEMP);
      if (j == mbase + r) e = 0.f;            // ~eye (only hits in colh 0)
      pD[r] += e;
      if (colh == 0) pP[r] += e;              // fg columns = tiles 0..63
    }
  }

  #pragma unroll
  for (int o = 1; o < 16; o <<= 1) {
    #pragma unroll
    for (int r = 0; r < 4; ++r) {
      pD[r] += __shfl_xor(pD[r], o);
      pP[r] += __shfl_xor(pP[r], o);
    }
  }
  if (col == 0) {
    #pragma unroll
    for (int r = 0; r < 4; ++r) {
      redD[rt][colh][quad * 4 + r] = pD[r];
      if (colh == 0) redP[rt][quad * 4 + r] = pP[r];
    }
  }
  __syncthreads();

  float term = 0.f;
  if (tid < 32) {
    int lrt = tid >> 4, lr = tid & 15;
    float dsum = fmaxf(redD[lrt][0][lr] + redD[lrt][1][lr], 1e-8f);
    float psum = fmaxf(redP[lrt][lr], 1e-8f);
    term = __logf(dsum) - __logf(psum);
  }
  if (tid < 64) {
    #pragma unroll
    for (int o = 32; o > 0; o >>= 1) term += __shfl_xor(term, o);
    if (tid == 0) atomicAdd(out, term * (1.0f / (NFG * NIMG)));
  }
}

// ---------------- launcher ---------------------------------------------------
extern "C" void kernel_launch(void* const* d_in, const int* in_sizes, int n_in,
                              void* d_out, int out_size, void* d_ws, size_t ws_size,
                              hipStream_t stream) {
  const float* feats = (const float*)d_in[0];
  const int* labels  = (const int*)d_in[1];
  float* out = (float*)d_out;

  char* ws = (char*)d_ws;
  uint32_t* TG      = (uint32_t*)(ws);                      // 192 B
  // --- zero region @4096: cnt(128) + candcnt(128) + map(1 MB) -------------
  uint32_t* cnt     = (uint32_t*)(ws + 4096);
  uint32_t* candcnt = (uint32_t*)(ws + 4224);
  ushort*   map     = (ushort*)(ws + 4352);                 // ends 1052928
  float4*   zreg    = (float4*)(ws + 4096);
  // ------------------------------------------------------------------------
  unsigned long long* cand = (unsigned long long*)(ws + 1052928); // 192 KB
  uint32_t* mgrp    = (uint32_t*)(ws + 2097152);            // 2 MB [8][65536]
  uint32_t* hist32  = (uint32_t*)(ws + 4194304);            // 768 KB [8][32][768]
  float*    ft      = (float*)(ws + 8388608);               // 10.5 MB [8][64][5120]
  ushort*   fs      = (ushort*)(ws + 18874368);             // 2 MB bf16 [8][2048][64]

  hipLaunchKernelGGL(prep_hash, dim3(NIMG * 32), dim3(256), 0, stream,
                     labels, zreg, mgrp, hist32, out);
  hipLaunchKernelGGL(topk_map, dim3(NIMG * 32), dim3(256), 0, stream,
                     mgrp, hist32, TG, cnt, candcnt, cand, map);
  hipLaunchKernelGGL(stream_compact, dim3(2048), dim3(256), 0, stream,
                     feats, map, ft);
  hipLaunchKernelGGL(norm_write, dim3(NIMG * 16), dim3(128), 0, stream,
                     ft, TG, candcnt, cand, fs);
  hipLaunchKernelGGL(loss_mfma, dim3(NIMG * (NFG / 32)), dim3(256), 0, stream,
                     fs, out);
}

// Round 3
// 239.854 us; speedup vs baseline: 1.3857x; 1.1460x over previous
//
#include <hip/hip_runtime.h>
#include <stdint.h>

#define NPIX   65536
#define NIMG   8
#define NCH    64
#define KSEL   2048
#define NFG    1024
#define NRING  768
#define NBG    256
#define INV_TEMP 14.285714285714286f   // 1/0.07

typedef __attribute__((ext_vector_type(8))) short bf16x8;
typedef __attribute__((ext_vector_type(4))) float f32x4;

// ---------------- Threefry-2x32 (20 rounds), exactly as JAX's lowering ------
__device__ __forceinline__ void tf2x32(uint32_t k0, uint32_t k1,
                                       uint32_t& x0, uint32_t& x1) {
  const uint32_t ks2 = k0 ^ k1 ^ 0x1BD11BDAu;
  x0 += k0; x1 += k1;
#define TF_RND(r) { x0 += x1; x1 = (x1 << (r)) | (x1 >> (32 - (r))); x1 ^= x0; }
  TF_RND(13) TF_RND(15) TF_RND(26) TF_RND(6)
  x0 += k1;  x1 += ks2 + 1u;
  TF_RND(17) TF_RND(29) TF_RND(16) TF_RND(24)
  x0 += ks2; x1 += k0 + 2u;
  TF_RND(13) TF_RND(15) TF_RND(26) TF_RND(6)
  x0 += k0;  x1 += k1 + 3u;
  TF_RND(17) TF_RND(29) TF_RND(16) TF_RND(24)
  x0 += k1;  x1 += ks2 + 4u;
  TF_RND(13) TF_RND(15) TF_RND(26) TF_RND(6)
  x0 += ks2; x1 += k0 + 5u;
#undef TF_RND
}

// float -> bf16 round-to-nearest-even
__device__ __forceinline__ ushort f2bf(float f) {
  uint32_t u = __float_as_uint(f);
  return (ushort)((u + 0x7FFFu + ((u >> 16) & 1u)) >> 16);
}

// ---------------- K1: fused dilation + hash + per-band histogram ------------
// 256 blocks = 8 images x 32 bands of 8 rows (halo 10 each side -> 28 rows).
// Parallel per-block keygen; non-atomic per-band hist (summed in K2).
__global__ __launch_bounds__(256) void prep_hash(const int* __restrict__ labels,
                                                 float4* __restrict__ zreg,
                                                 uint32_t* __restrict__ mgrp,
                                                 uint32_t* __restrict__ hist32,
                                                 float* __restrict__ out) {
  __shared__ uint64_t fgs[112], hds[112], fgb[32], dlb[32];  // 28 rows x 4 words
  __shared__ uint32_t lh[768];
  __shared__ uint32_t skeys[6];
  const int tid = threadIdx.x;
  const int img = blockIdx.x >> 5;
  const int band = blockIdx.x & 31;

  // zero cnt (128 B) + candcnt (128 B): 16 float4, block 0 only
  if (blockIdx.x == 0) {
    if (tid < 16) zreg[tid] = make_float4(0.f, 0.f, 0.f, 0.f);
    if (tid == 0) out[0] = 0.0f;
  }

  // JAX partitionable split: key(1) fold img, then fold group g
  if (tid < 3) {
    uint32_t kb0 = 0u, kb1 = (uint32_t)img;
    tf2x32(0u, 1u, kb0, kb1);
    uint32_t x0 = 0u, x1 = (uint32_t)tid;
    tf2x32(kb0, kb1, x0, x1);
    skeys[tid * 2 + 0] = x0;
    skeys[tid * 2 + 1] = x1;
  }
  for (int t = tid; t < 768; t += 256) lh[t] = 0;

  // pack fg bits for rows [band*8-10, band*8+18) (clamped rows contribute 0)
  const int rbase = band * 8 - 10;
  for (int it = 0; it < 28; ++it) {
    int hr = rbase + it;
    bool bit = false;
    if (hr >= 0 && hr < 256) bit = (labels[(img << 16) + (hr << 8) + tid] == 1);
    uint64_t m = __ballot(bit);
    if ((tid & 63) == 0) fgs[it * 4 + (tid >> 6)] = m;
  }
  __syncthreads();

  // horizontal dilation radius 10 within each row
  for (int w = tid; w < 112; w += 256) {
    int wc = w & 3;
    uint64_t x = fgs[w];
    uint64_t L = wc > 0 ? fgs[w - 1] : 0ull;
    uint64_t R = wc < 3 ? fgs[w + 1] : 0ull;
    uint64_t acc = x;
    #pragma unroll
    for (int s = 1; s <= 10; ++s) {
      acc |= (x << s) | (L >> (64 - s));
      acc |= (x >> s) | (R << (64 - s));
    }
    hds[w] = acc;
  }
  __syncthreads();

  // vertical dilation radius 10 for the band's 8 output rows
  for (int w = tid; w < 32; w += 256) {
    int r = w >> 2, wc = w & 3;
    uint64_t acc = 0ull;
    #pragma unroll
    for (int dr = 0; dr <= 20; ++dr) acc |= hds[(r + dr) * 4 + wc];
    fgb[w] = fgs[(r + 10) * 4 + wc];
    dlb[w] = acc;
  }
  __syncthreads();

  const uint32_t K00 = skeys[0], K01 = skeys[1];
  const uint32_t K10 = skeys[2], K11 = skeys[3];
  const uint32_t K20 = skeys[4], K21 = skeys[5];
  const int pbase = blockIdx.x * 2048;        // == img*65536 + band*2048

  #pragma unroll
  for (int k = 0; k < 8; ++k) {
    int off = k * 256 + tid;                  // 0..2047 within band
    int pix = (pbase + off) & 65535;
    int lw = off >> 6, bp = off & 63;
    uint32_t fgbit = (uint32_t)((fgb[lw] >> bp) & 1ull);
    uint32_t dilbit = (uint32_t)((dlb[lw] >> bp) & 1ull);
    uint32_t grp = fgbit ? 0u : (dilbit ? 1u : 2u);
    uint32_t k0 = grp == 0 ? K00 : grp == 1 ? K10 : K20;
    uint32_t k1 = grp == 0 ? K01 : grp == 1 ? K11 : K21;
    uint32_t x0 = 0u, x1 = (uint32_t)pix;
    tf2x32(k0, k1, x0, x1);
    uint32_t m = (x0 ^ x1) >> 9;
    mgrp[pbase + off] = (m << 2) | grp;
    atomicAdd(&lh[grp * 256 + (m >> 15)], 1u);
  }
  __syncthreads();
  // non-atomic per-band histogram part -> no pre-zero, no global atomics
  for (int t = tid; t < 768; t += 256) hist32[blockIdx.x * 768 + t] = lh[t];
}

// ---------------- K2: thresholds (inline) + emit indices --------------------
__global__ __launch_bounds__(256) void topk_emit(const uint32_t* __restrict__ mgrp,
                                                 const uint32_t* __restrict__ hist32,
                                                 uint32_t* __restrict__ TG,
                                                 uint32_t* __restrict__ cnt,
                                                 uint32_t* __restrict__ candcnt,
                                                 unsigned long long* __restrict__ cand,
                                                 int* __restrict__ idx_out) {
  __shared__ uint32_t hh[768];
  __shared__ uint32_t sT[3], loc[3], lbd[3], basA[3], basB[3];
  const int tid = threadIdx.x;
  const int b = blockIdx.x >> 5;
  const int base = blockIdx.x * 2048;
  for (int t = tid; t < 768; t += 256) {
    uint32_t s = 0;
    const uint32_t* hp = hist32 + (size_t)b * 32 * 768 + t;
    #pragma unroll
    for (int band = 0; band < 32; ++band) s += hp[band * 768];
    hh[t] = s;
  }
  if (tid < 3) { loc[tid] = 0; lbd[tid] = 0; }
  __syncthreads();

  if (tid < 3) {
    uint32_t nsel = tid == 0 ? NFG : tid == 1 ? NRING : NBG;
    const uint32_t* h = hh + tid * 256;
    uint32_t cum = 0; int T = 255;
    for (; T > 0; --T) {
      uint32_t c = h[T];
      if (cum + c >= nsel) break;
      cum += c;
    }
    sT[tid] = (uint32_t)T;
    if ((blockIdx.x & 31) == 0) {
      TG[(b * 3 + tid) * 2] = (uint32_t)T;
      TG[(b * 3 + tid) * 2 + 1] = cum;      // count strictly above bucket T
    }
  }
  __syncthreads();
  const uint32_t T0 = sT[0], T1 = sT[1], T2 = sT[2];

  #pragma unroll
  for (int k = 0; k < 8; ++k) {
    uint32_t v = mgrp[base + k * 256 + tid];
    uint32_t g = v & 3u, bin = v >> 17;
    uint32_t T = g == 0 ? T0 : g == 1 ? T1 : T2;
    if (bin > T) atomicAdd(&loc[g], 1u);
    else if (bin == T) atomicAdd(&lbd[g], 1u);
  }
  __syncthreads();
  if (tid < 3) {
    basA[tid] = atomicAdd(&cnt[b * 3 + tid], loc[tid]);
    basB[tid] = atomicAdd(&candcnt[b * 3 + tid], lbd[tid]);
    loc[tid] = 0; lbd[tid] = 0;
  }
  __syncthreads();

  #pragma unroll
  for (int k = 0; k < 8; ++k) {
    int p = base + k * 256 + tid;
    uint32_t v = mgrp[p];
    uint32_t g = v & 3u, bin = v >> 17;
    uint32_t T = g == 0 ? T0 : g == 1 ? T1 : T2;
    int pix = p & 65535;
    if (bin > T) {
      uint32_t o = atomicAdd(&loc[g], 1u);
      int seg = g == 0 ? 0 : g == 1 ? NFG : (NFG + NRING);
      idx_out[b * KSEL + seg + (int)(basA[g] + o)] = pix;
    } else if (bin == T) {
      uint32_t o = atomicAdd(&lbd[g], 1u);
      uint32_t c = basB[g] + o;
      uint32_t m = v >> 2;
      if (c < 1024u)
        cand[((size_t)b * 3 + g) * 1024 + c] =
            ((unsigned long long)m << 16) | (uint32_t)pix;
    }
  }
}

// ---------------- K3: gather + fused tie-break rank -> bf16 rows ------------
// Output fs[img][j][64] row-major bf16 == MFMA A/B fragment-friendly layout.
// feats is L3-resident (128 MB < 256 MB Infinity Cache): scattered 4B lane
// loads hit L3; ~64 MB line traffic total.
#define GA 16
__global__ __launch_bounds__(256) void gather_rank_t(
    const float* __restrict__ feats, const int* __restrict__ idx,
    const uint32_t* __restrict__ TG, const uint32_t* __restrict__ candcnt,
    const unsigned long long* __restrict__ cand, ushort* __restrict__ fs) {
  __shared__ float tile[GA * 65];
  __shared__ float ssb[16 * GA];
  __shared__ float sscale[GA];
  __shared__ int lidx[GA];
  __shared__ unsigned long long cb[1024];
  const int tid = threadIdx.x;
  const int img = blockIdx.x >> 7;            // 128 blocks per image
  const int win = (blockIdx.x & 127) * GA;    // anchor window within image
  int seg, segoff, nsel;
  if (win < NFG)               { seg = 0; segoff = 0;            nsel = NFG; }
  else if (win < NFG + NRING)  { seg = 1; segoff = NFG;          nsel = NRING; }
  else                         { seg = 2; segoff = NFG + NRING;  nsel = NBG; }
  const int task = img * 3 + seg;
  const uint32_t G = TG[task * 2 + 1];
  const int poslo = win - segoff;

  if (tid < GA) {
    if ((uint32_t)(poslo + tid) < G)
      lidx[tid] = idx[img * KSEL + win + tid];
  }
  const bool needRank = (uint32_t)(poslo + GA) > G;   // block-uniform
  if (needRank) {
    const int c = (int)(candcnt[task] < 1024u ? candcnt[task] : 1024u);
    const int r = nsel - (int)G;
    for (int i = tid; i < c; i += 256) cb[i] = cand[task * 1024 + i];
    __syncthreads();
    for (int i = tid; i < c; i += 256) {
      unsigned long long me = cb[i];
      uint32_t mm = (uint32_t)(me >> 16), pi = (uint32_t)(me & 0xFFFFu);
      int rank = 0;
      for (int j = 0; j < c; ++j) {
        unsigned long long o = cb[j];
        uint32_t om = (uint32_t)(o >> 16), op = (uint32_t)(o & 0xFFFFu);
        if (om > mm || (om == mm && op < pi)) ++rank;
      }
      if (rank < r) {
        int slot = (int)G + rank - poslo;
        if (slot >= 0 && slot < GA) lidx[slot] = (int)pi;
      }
    }
  }
  __syncthreads();

  // gather: a = tid&15 anchor, q = tid>>4 handles channels q*4 .. q*4+3
  const int a = tid & 15, q = tid >> 4;
  const int pix = lidx[a];
  const float* fb = feats + ((size_t)img * NCH + q * 4) * NPIX + pix;
  float ss = 0.f;
  #pragma unroll
  for (int k = 0; k < 4; ++k) {
    float v = fb[(size_t)k * NPIX];
    tile[a * 65 + q * 4 + k] = v;
    ss += v * v;
  }
  ssb[q * GA + a] = ss;
  __syncthreads();
  if (q == 0) {
    float tot = 0.f;
    #pragma unroll
    for (int q2 = 0; q2 < 16; ++q2) tot += ssb[q2 * GA + a];
    sscale[a] = 1.0f / fmaxf(sqrtf(tot), 1e-12f);
  }
  __syncthreads();

  // write phase: thread (row = tid>>4, chunk = tid&15) -> contiguous ushort4
  const int row = tid >> 4, c4 = tid & 15;
  const float sc = sscale[row];
  ushort4 v4;
  v4.x = f2bf(tile[row * 65 + c4 * 4 + 0] * sc);
  v4.y = f2bf(tile[row * 65 + c4 * 4 + 1] * sc);
  v4.z = f2bf(tile[row * 65 + c4 * 4 + 2] * sc);
  v4.w = f2bf(tile[row * 65 + c4 * 4 + 3] * sc);
  ((ushort4*)(fs + ((size_t)img * KSEL + win + row) * NCH))[c4] = v4;
}

// ---------------- K4: MFMA loss ---------------------------------------------
__global__ __launch_bounds__(256) void loss_mfma(const ushort* __restrict__ fs,
                                                 float* __restrict__ out) {
  const int img = blockIdx.x & 7;             // XCD swizzle
  const int a0 = (blockIdx.x >> 3) * 32;
  const ushort* X = fs + (size_t)img * KSEL * NCH;
  const int tid = threadIdx.x;
  const int lane = tid & 63, wave = tid >> 6;
  const int quad = lane >> 4, col = lane & 15;
  const int rt = wave >> 1, colh = wave & 1;

  __shared__ float redD[2][2][16];
  __shared__ float redP[2][16];

  // A fragment: m = lane&15, k = quad*8 + [0..7]; two K-halves of 32
  const int arow = a0 + rt * 16 + col;
  const bf16x8* Ap = (const bf16x8*)(X + (size_t)arow * NCH + quad * 8);
  const bf16x8 a_lo = Ap[0];
  const bf16x8 a_hi = Ap[4];                  // +32 channels = +64 B

  float pD[4] = {0.f, 0.f, 0.f, 0.f};
  float pP[4] = {0.f, 0.f, 0.f, 0.f};
  const int ct0 = colh * 64;
  const int mbase = a0 + rt * 16 + quad * 4;  // D rows for this lane

  for (int ct = ct0; ct < ct0 + 64; ++ct) {
    const int j = ct * 16 + col;              // D column for this lane
    const bf16x8* Bp = (const bf16x8*)(X + (size_t)j * NCH + quad * 8);
    bf16x8 b_lo = Bp[0];
    bf16x8 b_hi = Bp[4];
    f32x4 d = {0.f, 0.f, 0.f, 0.f};
    d = __builtin_amdgcn_mfma_f32_16x16x32_bf16(a_lo, b_lo, d, 0, 0, 0);
    d = __builtin_amdgcn_mfma_f32_16x16x32_bf16(a_hi, b_hi, d, 0, 0, 0);
    #pragma unroll
    for (int r = 0; r < 4; ++r) {
      float e = __expf(d[r] * INV_TEMP);
      if (j == mbase + r) e = 0.f;            // ~eye (only hits in colh 0)
      pD[r] += e;
      if (colh == 0) pP[r] += e;              // fg columns = tiles 0..63
    }
  }

  // reduce across the 16 columns held by this quad's lanes
  #pragma unroll
  for (int o = 1; o < 16; o <<= 1) {
    #pragma unroll
    for (int r = 0; r < 4; ++r) {
      pD[r] += __shfl_xor(pD[r], o);
      pP[r] += __shfl_xor(pP[r], o);
    }
  }
  if (col == 0) {
    #pragma unroll
    for (int r = 0; r < 4; ++r) {
      redD[rt][colh][quad * 4 + r] = pD[r];
      if (colh == 0) redP[rt][quad * 4 + r] = pP[r];
    }
  }
  __syncthreads();

  float term = 0.f;
  if (tid < 32) {
    int lrt = tid >> 4, lr = tid & 15;
    float dsum = fmaxf(redD[lrt][0][lr] + redD[lrt][1][lr], 1e-8f);
    float psum = fmaxf(redP[lrt][lr], 1e-8f);
    term = __logf(dsum) - __logf(psum);
  }
  if (tid < 64) {
    #pragma unroll
    for (int o = 32; o > 0; o >>= 1) term += __shfl_xor(term, o);
    if (tid == 0) atomicAdd(out, term * (1.0f / (NFG * NIMG)));
  }
}

// ---------------- launcher ---------------------------------------------------
extern "C" void kernel_launch(void* const* d_in, const int* in_sizes, int n_in,
                              void* d_out, int out_size, void* d_ws, size_t ws_size,
                              hipStream_t stream) {
  const float* feats = (const float*)d_in[0];
  const int* labels  = (const int*)d_in[1];
  float* out = (float*)d_out;

  char* ws = (char*)d_ws;
  uint32_t* TG      = (uint32_t*)(ws);                      // 192 B
  // --- zero region @4096: cnt (128 B) + candcnt (128 B) -------------------
  uint32_t* cnt     = (uint32_t*)(ws + 4096);
  uint32_t* candcnt = (uint32_t*)(ws + 4224);
  float4*   zreg    = (float4*)(ws + 4096);                 // 16 float4
  // ------------------------------------------------------------------------
  unsigned long long* cand = (unsigned long long*)(ws + 8192);   // 192 KB
  int*      idx     = (int*)(ws + 262144);                  // 64 KB
  uint32_t* mgrp    = (uint32_t*)(ws + 2097152);            // 2 MB [8][65536]
  uint32_t* hist32  = (uint32_t*)(ws + 4194304);            // 768 KB [8][32][768]
  ushort*   fs      = (ushort*)(ws + 8388608);              // 2 MB bf16 [8][2048][64]

  hipLaunchKernelGGL(prep_hash, dim3(NIMG * 32), dim3(256), 0, stream,
                     labels, zreg, mgrp, hist32, out);
  hipLaunchKernelGGL(topk_emit, dim3(NIMG * 32), dim3(256), 0, stream,
                     mgrp, hist32, TG, cnt, candcnt, cand, idx);
  hipLaunchKernelGGL(gather_rank_t, dim3((NIMG * KSEL) / GA), dim3(256), 0, stream,
                     feats, idx, TG, candcnt, cand, fs);
  hipLaunchKernelGGL(loss_mfma, dim3(NIMG * (NFG / 32)), dim3(256), 0, stream,
                     fs, out);
}

// Round 4
// 234.502 us; speedup vs baseline: 1.4173x; 1.0228x over previous
//
#include <hip/hip_runtime.h>
#include <stdint.h>

#define NPIX   65536
#define NIMG   8
#define NCH    64
#define KSEL   2048
#define NFG    1024
#define NRING  768
#define NBG    256
#define INV_TEMP 14.285714285714286f   // 1/0.07

typedef __attribute__((ext_vector_type(8))) short bf16x8;
typedef __attribute__((ext_vector_type(4))) float f32x4;

// ---------------- Threefry-2x32 (20 rounds), exactly as JAX's lowering ------
__device__ __forceinline__ void tf2x32(uint32_t k0, uint32_t k1,
                                       uint32_t& x0, uint32_t& x1) {
  const uint32_t ks2 = k0 ^ k1 ^ 0x1BD11BDAu;
  x0 += k0; x1 += k1;
#define TF_RND(r) { x0 += x1; x1 = (x1 << (r)) | (x1 >> (32 - (r))); x1 ^= x0; }
  TF_RND(13) TF_RND(15) TF_RND(26) TF_RND(6)
  x0 += k1;  x1 += ks2 + 1u;
  TF_RND(17) TF_RND(29) TF_RND(16) TF_RND(24)
  x0 += ks2; x1 += k0 + 2u;
  TF_RND(13) TF_RND(15) TF_RND(26) TF_RND(6)
  x0 += k0;  x1 += k1 + 3u;
  TF_RND(17) TF_RND(29) TF_RND(16) TF_RND(24)
  x0 += k1;  x1 += ks2 + 4u;
  TF_RND(13) TF_RND(15) TF_RND(26) TF_RND(6)
  x0 += ks2; x1 += k0 + 5u;
#undef TF_RND
}

// float -> bf16 round-to-nearest-even
__device__ __forceinline__ ushort f2bf(float f) {
  uint32_t u = __float_as_uint(f);
  return (ushort)((u + 0x7FFFu + ((u >> 16) & 1u)) >> 16);
}

// ---------------- K1: fused dilation + hash + per-band histogram ------------
// 256 blocks = 8 images x 32 bands of 8 rows (halo 10 each side -> 28 rows).
// Parallel per-block keygen; non-atomic per-band hist (summed in K2).
__global__ __launch_bounds__(256) void prep_hash(const int* __restrict__ labels,
                                                 uint32_t* __restrict__ mgrp,
                                                 uint32_t* __restrict__ hist32,
                                                 float* __restrict__ out) {
  __shared__ uint64_t fgs[112], hds[112], fgb[32], dlb[32];  // 28 rows x 4 words
  __shared__ uint32_t lh[768];
  __shared__ uint32_t skeys[6];
  const int tid = threadIdx.x;
  const int img = blockIdx.x >> 5;
  const int band = blockIdx.x & 31;

  if (blockIdx.x == 0 && tid == 0) out[0] = 0.0f;

  // JAX partitionable split: key(1) fold img, then fold group g
  if (tid < 3) {
    uint32_t kb0 = 0u, kb1 = (uint32_t)img;
    tf2x32(0u, 1u, kb0, kb1);
    uint32_t x0 = 0u, x1 = (uint32_t)tid;
    tf2x32(kb0, kb1, x0, x1);
    skeys[tid * 2 + 0] = x0;
    skeys[tid * 2 + 1] = x1;
  }
  for (int t = tid; t < 768; t += 256) lh[t] = 0;

  // pack fg bits for rows [band*8-10, band*8+18) (clamped rows contribute 0)
  const int rbase = band * 8 - 10;
  for (int it = 0; it < 28; ++it) {
    int hr = rbase + it;
    bool bit = false;
    if (hr >= 0 && hr < 256) bit = (labels[(img << 16) + (hr << 8) + tid] == 1);
    uint64_t m = __ballot(bit);
    if ((tid & 63) == 0) fgs[it * 4 + (tid >> 6)] = m;
  }
  __syncthreads();

  // horizontal dilation radius 10 within each row
  for (int w = tid; w < 112; w += 256) {
    int wc = w & 3;
    uint64_t x = fgs[w];
    uint64_t L = wc > 0 ? fgs[w - 1] : 0ull;
    uint64_t R = wc < 3 ? fgs[w + 1] : 0ull;
    uint64_t acc = x;
    #pragma unroll
    for (int s = 1; s <= 10; ++s) {
      acc |= (x << s) | (L >> (64 - s));
      acc |= (x >> s) | (R << (64 - s));
    }
    hds[w] = acc;
  }
  __syncthreads();

  // vertical dilation radius 10 for the band's 8 output rows
  for (int w = tid; w < 32; w += 256) {
    int r = w >> 2, wc = w & 3;
    uint64_t acc = 0ull;
    #pragma unroll
    for (int dr = 0; dr <= 20; ++dr) acc |= hds[(r + dr) * 4 + wc];
    fgb[w] = fgs[(r + 10) * 4 + wc];
    dlb[w] = acc;
  }
  __syncthreads();

  const uint32_t K00 = skeys[0], K01 = skeys[1];
  const uint32_t K10 = skeys[2], K11 = skeys[3];
  const uint32_t K20 = skeys[4], K21 = skeys[5];
  const int pbase = blockIdx.x * 2048;        // == img*65536 + band*2048

  #pragma unroll
  for (int k = 0; k < 8; ++k) {
    int off = k * 256 + tid;                  // 0..2047 within band
    int pix = (pbase + off) & 65535;
    int lw = off >> 6, bp = off & 63;
    uint32_t fgbit = (uint32_t)((fgb[lw] >> bp) & 1ull);
    uint32_t dilbit = (uint32_t)((dlb[lw] >> bp) & 1ull);
    uint32_t grp = fgbit ? 0u : (dilbit ? 1u : 2u);
    uint32_t k0 = grp == 0 ? K00 : grp == 1 ? K10 : K20;
    uint32_t k1 = grp == 0 ? K01 : grp == 1 ? K11 : K21;
    uint32_t x0 = 0u, x1 = (uint32_t)pix;
    tf2x32(k0, k1, x0, x1);
    uint32_t m = (x0 ^ x1) >> 9;
    mgrp[pbase + off] = (m << 2) | grp;
    atomicAdd(&lh[grp * 256 + (m >> 15)], 1u);
  }
  __syncthreads();
  // non-atomic per-band histogram part -> no pre-zero, no global atomics
  for (int t = tid; t < 768; t += 256) hist32[blockIdx.x * 768 + t] = lh[t];
}

// ---------------- K2: thresholds + ORDERED emission (ballot scans) ----------
// Emits idx in globally sorted pixel order per segment (DRAM page locality for
// the gather) and cand in sorted pixel order. Zero atomics, zero pre-zeroing.
__global__ __launch_bounds__(256) void topk_emit(const uint32_t* __restrict__ mgrp,
                                                 const uint32_t* __restrict__ hist32,
                                                 uint32_t* __restrict__ TG,
                                                 uint32_t* __restrict__ candcnt,
                                                 unsigned long long* __restrict__ cand,
                                                 int* __restrict__ idx_out) {
  __shared__ uint32_t hh[768];
  __shared__ uint32_t sT[3];
  __shared__ uint32_t cA[3][32], cB[3][32];   // per-band counts above/at T
  __shared__ uint32_t preA[3], preB[3];       // counts in preceding bands
  __shared__ uint32_t runA[3], runB[3];       // running intra-block counts
  __shared__ uint32_t wcA[3][4], wcB[3][4];   // per-wave chunk counts
  const int tid = threadIdx.x;
  const int b = blockIdx.x >> 5;
  const int band = blockIdx.x & 31;
  const int base = blockIdx.x * 2048;

  // prefetch this block's 2048 mgrp entries (8 in flight)
  uint32_t vv[8];
  #pragma unroll
  for (int k = 0; k < 8; ++k) vv[k] = mgrp[base + k * 256 + tid];

  // full-image histogram
  for (int t = tid; t < 768; t += 256) {
    uint32_t s = 0;
    const uint32_t* hp = hist32 + (size_t)b * 24576 + t;
    #pragma unroll
    for (int bd = 0; bd < 32; ++bd) s += hp[bd * 768];
    hh[t] = s;
  }
  __syncthreads();

  if (tid < 3) {
    uint32_t nsel = tid == 0 ? NFG : tid == 1 ? NRING : NBG;
    const uint32_t* h = hh + tid * 256;
    uint32_t cum = 0; int T = 255;
    for (; T > 0; --T) {
      uint32_t c = h[T];
      if (cum + c >= nsel) break;
      cum += c;
    }
    sT[tid] = (uint32_t)T;
    runA[tid] = 0; runB[tid] = 0;
    if (band == 0) {
      TG[(b * 3 + tid) * 2] = (uint32_t)T;
      TG[(b * 3 + tid) * 2 + 1] = cum;        // G: count strictly above T
      candcnt[b * 3 + tid] = h[T];            // total ties at T
    }
  }
  __syncthreads();
  const uint32_t T0 = sT[0], T1 = sT[1], T2 = sT[2];

  // per-(g, band') above/tie counts; ~7-15 buckets above T typically
  if (tid < 96) {
    int g = tid >> 5, bd = tid & 31;
    uint32_t T = g == 0 ? T0 : g == 1 ? T1 : T2;
    const uint32_t* hp = hist32 + (size_t)b * 24576 + bd * 768 + g * 256;
    uint32_t sA = 0;
    for (int t = (int)T + 1; t < 256; ++t) sA += hp[t];
    cA[g][bd] = sA;
    cB[g][bd] = hp[T];
  }
  __syncthreads();
  if (tid < 3) {
    uint32_t pa = 0, pb = 0;
    for (int bd = 0; bd < band; ++bd) { pa += cA[tid][bd]; pb += cB[tid][bd]; }
    preA[tid] = pa; preB[tid] = pb;
  }
  __syncthreads();

  const int lane = tid & 63, w = tid >> 6;
  #pragma unroll 1
  for (int k = 0; k < 8; ++k) {
    const uint32_t v = vv[k];
    const uint32_t g = v & 3u, bin = v >> 17;
    const uint32_t T = g == 0 ? T0 : g == 1 ? T1 : T2;
    const bool selA = bin > T;
    const bool selB = bin == T;
    const uint64_t mA0 = __ballot(selA && g == 0);
    const uint64_t mA1 = __ballot(selA && g == 1);
    const uint64_t mA2 = __ballot(selA && g == 2);
    const uint64_t mB0 = __ballot(selB && g == 0);
    const uint64_t mB1 = __ballot(selB && g == 1);
    const uint64_t mB2 = __ballot(selB && g == 2);
    if (lane == 0) {
      wcA[0][w] = (uint32_t)__popcll(mA0);
      wcA[1][w] = (uint32_t)__popcll(mA1);
      wcA[2][w] = (uint32_t)__popcll(mA2);
      wcB[0][w] = (uint32_t)__popcll(mB0);
      wcB[1][w] = (uint32_t)__popcll(mB1);
      wcB[2][w] = (uint32_t)__popcll(mB2);
    }
    __syncthreads();
    if (selA || selB) {
      const uint64_t mask = g == 0 ? (selA ? mA0 : mB0)
                          : g == 1 ? (selA ? mA1 : mB1)
                                   : (selA ? mA2 : mB2);
      const uint32_t intra = (uint32_t)__popcll(mask & ((1ull << lane) - 1ull));
      uint32_t wbase = 0;
      for (int w2 = 0; w2 < w; ++w2) wbase += selA ? wcA[g][w2] : wcB[g][w2];
      const int pix = (base + k * 256 + tid) & 65535;
      if (selA) {
        const uint32_t slot = preA[g] + runA[g] + wbase + intra;
        const int seg = g == 0 ? 0 : g == 1 ? NFG : (NFG + NRING);
        idx_out[b * KSEL + seg + (int)slot] = pix;
      } else {
        const uint32_t c = preB[g] + runB[g] + wbase + intra;
        if (c < 1024u) {
          const uint32_t m = v >> 2;
          cand[((size_t)b * 3 + g) * 1024 + c] =
              ((unsigned long long)m << 16) | (uint32_t)pix;
        }
      }
    }
    __syncthreads();
    if (tid < 3) {
      runA[tid] += wcA[tid][0] + wcA[tid][1] + wcA[tid][2] + wcA[tid][3];
      runB[tid] += wcB[tid][0] + wcB[tid][1] + wcB[tid][2] + wcB[tid][3];
    }
    __syncthreads();   // protect wc from next chunk's overwrite
  }
}

// ---------------- K3: gather + fused tie-break rank -> bf16 rows ------------
// idx is pixel-sorted per segment: each 16-anchor window spans ~512 adjacent
// pixels -> ~1 DRAM row per channel plane instead of 16 (row-activate bound).
#define GA 16
__global__ __launch_bounds__(256) void gather_rank_t(
    const float* __restrict__ feats, const int* __restrict__ idx,
    const uint32_t* __restrict__ TG, const uint32_t* __restrict__ candcnt,
    const unsigned long long* __restrict__ cand, ushort* __restrict__ fs) {
  __shared__ float tile[GA * 65];
  __shared__ float ssb[16 * GA];
  __shared__ float sscale[GA];
  __shared__ int lidx[GA];
  __shared__ unsigned long long cb[1024];
  const int tid = threadIdx.x;
  const int img = blockIdx.x >> 7;            // 128 blocks per image
  const int win = (blockIdx.x & 127) * GA;    // anchor window within image
  int seg, segoff, nsel;
  if (win < NFG)               { seg = 0; segoff = 0;            nsel = NFG; }
  else if (win < NFG + NRING)  { seg = 1; segoff = NFG;          nsel = NRING; }
  else                         { seg = 2; segoff = NFG + NRING;  nsel = NBG; }
  const int task = img * 3 + seg;
  const uint32_t G = TG[task * 2 + 1];
  const int poslo = win - segoff;

  if (tid < GA) {
    if ((uint32_t)(poslo + tid) < G)
      lidx[tid] = idx[img * KSEL + win + tid];
  }
  const bool needRank = (uint32_t)(poslo + GA) > G;   // block-uniform
  if (needRank) {
    const int c = (int)(candcnt[task] < 1024u ? candcnt[task] : 1024u);
    const int r = nsel - (int)G;
    for (int i = tid; i < c; i += 256) cb[i] = cand[task * 1024 + i];
    __syncthreads();
    for (int i = tid; i < c; i += 256) {
      unsigned long long me = cb[i];
      uint32_t mm = (uint32_t)(me >> 16), pi = (uint32_t)(me & 0xFFFFu);
      int rank = 0;
      for (int j = 0; j < c; ++j) {
        unsigned long long o = cb[j];
        uint32_t om = (uint32_t)(o >> 16), op = (uint32_t)(o & 0xFFFFu);
        if (om > mm || (om == mm && op < pi)) ++rank;
      }
      if (rank < r) {
        int slot = (int)G + rank - poslo;
        if (slot >= 0 && slot < GA) lidx[slot] = (int)pi;
      }
    }
  }
  __syncthreads();

  // gather: a = tid&15 anchor, q = tid>>4 handles channels q*4 .. q*4+3
  const int a = tid & 15, q = tid >> 4;
  const int pix = lidx[a];
  const float* fb = feats + ((size_t)img * NCH + q * 4) * NPIX + pix;
  float ss = 0.f;
  #pragma unroll
  for (int k = 0; k < 4; ++k) {
    float v = fb[(size_t)k * NPIX];
    tile[a * 65 + q * 4 + k] = v;
    ss += v * v;
  }
  ssb[q * GA + a] = ss;
  __syncthreads();
  if (q == 0) {
    float tot = 0.f;
    #pragma unroll
    for (int q2 = 0; q2 < 16; ++q2) tot += ssb[q2 * GA + a];
    sscale[a] = 1.0f / fmaxf(sqrtf(tot), 1e-12f);
  }
  __syncthreads();

  // write phase: thread (row = tid>>4, chunk = tid&15) -> contiguous ushort4
  const int row = tid >> 4, c4 = tid & 15;
  const float sc = sscale[row];
  ushort4 v4;
  v4.x = f2bf(tile[row * 65 + c4 * 4 + 0] * sc);
  v4.y = f2bf(tile[row * 65 + c4 * 4 + 1] * sc);
  v4.z = f2bf(tile[row * 65 + c4 * 4 + 2] * sc);
  v4.w = f2bf(tile[row * 65 + c4 * 4 + 3] * sc);
  ((ushort4*)(fs + ((size_t)img * KSEL + win + row) * NCH))[c4] = v4;
}

// ---------------- K4: MFMA loss, 16 waves/block (4 waves/SIMD) ---------------
// 256 blocks = 8 img x 32 anchor-tiles; 1024 threads = 16 waves =
// (rt in 0..1) x (cseg in 0..7, 16 col-tiles each).
__global__ __launch_bounds__(1024) void loss_mfma(const ushort* __restrict__ fs,
                                                  float* __restrict__ out) {
  const int img = blockIdx.x & 7;             // XCD swizzle
  const int a0 = (blockIdx.x >> 3) * 32;
  const ushort* X = fs + (size_t)img * KSEL * NCH;
  const int tid = threadIdx.x;
  const int lane = tid & 63, wave = tid >> 6; // 0..15
  const int quad = lane >> 4, col = lane & 15;
  const int rt = wave >> 3, cseg = wave & 7;

  __shared__ float redD[2][8][16];
  __shared__ float redP[2][4][16];

  // A fragment: m = lane&15, k = quad*8 + [0..7]; two K-halves of 32
  const int arow = a0 + rt * 16 + col;
  const bf16x8* Ap = (const bf16x8*)(X + (size_t)arow * NCH + quad * 8);
  const bf16x8 a_lo = Ap[0];
  const bf16x8 a_hi = Ap[4];                  // +32 channels = +64 B

  float pD[4] = {0.f, 0.f, 0.f, 0.f};
  float pP[4] = {0.f, 0.f, 0.f, 0.f};
  const int ct0 = cseg * 16;
  const int mbase = a0 + rt * 16 + quad * 4;  // D rows for this lane

  for (int ct = ct0; ct < ct0 + 16; ++ct) {
    const int j = ct * 16 + col;              // D column for this lane
    const bf16x8* Bp = (const bf16x8*)(X + (size_t)j * NCH + quad * 8);
    bf16x8 b_lo = Bp[0];
    bf16x8 b_hi = Bp[4];
    f32x4 d = {0.f, 0.f, 0.f, 0.f};
    d = __builtin_amdgcn_mfma_f32_16x16x32_bf16(a_lo, b_lo, d, 0, 0, 0);
    d = __builtin_amdgcn_mfma_f32_16x16x32_bf16(a_hi, b_hi, d, 0, 0, 0);
    #pragma unroll
    for (int r = 0; r < 4; ++r) {
      float e = __expf(d[r] * INV_TEMP);
      if (j == mbase + r) e = 0.f;            // ~eye (only hits when cseg<4)
      pD[r] += e;
      if (cseg < 4) pP[r] += e;               // fg columns = tiles 0..63
    }
  }

  // reduce across the 16 columns held by this quad's lanes
  #pragma unroll
  for (int o = 1; o < 16; o <<= 1) {
    #pragma unroll
    for (int r = 0; r < 4; ++r) {
      pD[r] += __shfl_xor(pD[r], o);
      pP[r] += __shfl_xor(pP[r], o);
    }
  }
  if (col == 0) {
    #pragma unroll
    for (int r = 0; r < 4; ++r) {
      redD[rt][cseg][quad * 4 + r] = pD[r];
      if (cseg < 4) redP[rt][cseg][quad * 4 + r] = pP[r];
    }
  }
  __syncthreads();

  float term = 0.f;
  if (tid < 32) {
    int lrt = tid >> 4, lr = tid & 15;
    float dsum = 0.f, psum = 0.f;
    #pragma unroll
    for (int cs = 0; cs < 8; ++cs) dsum += redD[lrt][cs][lr];
    #pragma unroll
    for (int cs = 0; cs < 4; ++cs) psum += redP[lrt][cs][lr];
    dsum = fmaxf(dsum, 1e-8f);
    psum = fmaxf(psum, 1e-8f);
    term = __logf(dsum) - __logf(psum);
  }
  if (tid < 64) {
    #pragma unroll
    for (int o = 32; o > 0; o >>= 1) term += __shfl_xor(term, o);
    if (tid == 0) atomicAdd(out, term * (1.0f / (NFG * NIMG)));
  }
}

// ---------------- launcher ---------------------------------------------------
extern "C" void kernel_launch(void* const* d_in, const int* in_sizes, int n_in,
                              void* d_out, int out_size, void* d_ws, size_t ws_size,
                              hipStream_t stream) {
  const float* feats = (const float*)d_in[0];
  const int* labels  = (const int*)d_in[1];
  float* out = (float*)d_out;

  char* ws = (char*)d_ws;
  uint32_t* TG      = (uint32_t*)(ws);                      // 192 B
  uint32_t* candcnt = (uint32_t*)(ws + 4096);               // 96 B (plain-written)
  unsigned long long* cand = (unsigned long long*)(ws + 8192);   // 192 KB
  int*      idx     = (int*)(ws + 262144);                  // 64 KB
  uint32_t* mgrp    = (uint32_t*)(ws + 2097152);            // 2 MB [8][65536]
  uint32_t* hist32  = (uint32_t*)(ws + 4194304);            // 768 KB [8][32][768]
  ushort*   fs      = (ushort*)(ws + 8388608);              // 2 MB bf16 [8][2048][64]

  hipLaunchKernelGGL(prep_hash, dim3(NIMG * 32), dim3(256), 0, stream,
                     labels, mgrp, hist32, out);
  hipLaunchKernelGGL(topk_emit, dim3(NIMG * 32), dim3(256), 0, stream,
                     mgrp, hist32, TG, candcnt, cand, idx);
  hipLaunchKernelGGL(gather_rank_t, dim3((NIMG * KSEL) / GA), dim3(256), 0, stream,
                     feats, idx, TG, candcnt, cand, fs);
  hipLaunchKernelGGL(loss_mfma, dim3(NIMG * (NFG / 32)), dim3(1024), 0, stream,
                     fs, out);
}